// Round 1
// baseline (47581.854 us; speedup 1.0000x reference)
//
#include <hip/hip_runtime.h>
#include <stdint.h>

// ---------------------------------------------------------------------------
// Seq2Seq LSTM (2-layer enc + 2-layer autoregressive dec), B=256,H=512,T=288.
// Single cooperative persistent kernel; bf16 MFMA 16x16x32 w/ fp32 accum.
// ---------------------------------------------------------------------------

typedef __attribute__((ext_vector_type(8))) short bfx8;   // 8 bf16 (4 VGPRs)
typedef __attribute__((ext_vector_type(4))) float fx4;

#define NBLK 256
#define NTHR 256
#define BH   (256*512)

__device__ __forceinline__ unsigned short f2bf(float f){
  unsigned u = __float_as_uint(f);
  u += 0x7FFFu + ((u >> 16) & 1u);          // RNE
  return (unsigned short)(u >> 16);
}
__device__ __forceinline__ float bf2f(unsigned short b){
  return __uint_as_float(((unsigned)b) << 16);
}
__device__ __forceinline__ float sigm(float x){ return 1.0f/(1.0f + __expf(-x)); }
__device__ __forceinline__ float tanhf_(float x){
  x = fminf(12.0f, fmaxf(-12.0f, x));
  float e = __expf(2.0f*x);
  return (e - 1.0f)/(e + 1.0f);
}

// Low-contention grid barrier: per-block slots + block0 sweep + broadcast flag.
// bar[0] = flag; slots at bar[16 + blk*16]. Monotone targets -> no reset races.
__device__ __forceinline__ void gridbar(unsigned* bar, unsigned target){
  __syncthreads();
  if (blockIdx.x == 0){
    int i = threadIdx.x;
    if (i > 0 && i < NBLK){
      while (__hip_atomic_load(bar + 16 + i*16, __ATOMIC_ACQUIRE,
                               __HIP_MEMORY_SCOPE_AGENT) < target)
        __builtin_amdgcn_s_sleep(1);
    }
    __syncthreads();
    if (threadIdx.x == 0)
      __hip_atomic_store(bar, target, __ATOMIC_RELEASE, __HIP_MEMORY_SCOPE_AGENT);
  } else {
    if (threadIdx.x == 0){
      __hip_atomic_store(bar + 16 + blockIdx.x*16, target, __ATOMIC_RELEASE,
                         __HIP_MEMORY_SCOPE_AGENT);
      while (__hip_atomic_load(bar, __ATOMIC_ACQUIRE,
                               __HIP_MEMORY_SCOPE_AGENT) < target)
        __builtin_amdgcn_s_sleep(1);
    }
    __syncthreads();
  }
}

// Accumulate K=512: A rows from h (bf16), 4 gate columns of W ([2048][512] bf16).
__device__ __forceinline__ void accK512(fx4* acc, const uint16_t* aq,
                                        const uint16_t* w0, const uint16_t* w1,
                                        const uint16_t* w2, const uint16_t* w3){
  #pragma unroll
  for (int kc = 0; kc < 16; ++kc){
    bfx8 af = *(const bfx8*)(aq + kc*32);
    acc[0] = __builtin_amdgcn_mfma_f32_16x16x32_bf16(af, *(const bfx8*)(w0 + kc*32), acc[0], 0, 0, 0);
    acc[1] = __builtin_amdgcn_mfma_f32_16x16x32_bf16(af, *(const bfx8*)(w1 + kc*32), acc[1], 0, 0, 0);
    acc[2] = __builtin_amdgcn_mfma_f32_16x16x32_bf16(af, *(const bfx8*)(w2 + kc*32), acc[2], 0, 0, 0);
    acc[3] = __builtin_amdgcn_mfma_f32_16x16x32_bf16(af, *(const bfx8*)(w3 + kc*32), acc[3], 0, 0, 0);
  }
}

__device__ __forceinline__ void pointwise(fx4* acc, int bq, int u, float* cbuf, uint16_t* hout){
  #pragma unroll
  for (int r = 0; r < 4; ++r){
    int b = bq + r;
    float iv = sigm(acc[0][r]);
    float fv = sigm(acc[1][r]);
    float gv = tanhf_(acc[2][r]);
    float ov = sigm(acc[3][r]);
    float cn = fv * cbuf[b*512 + u] + iv * gv;
    cbuf[b*512 + u] = cn;
    hout[b*512 + u] = f2bf(ov * tanhf_(cn));
  }
}

// Layer-1 phase (shared enc/dec): g1 = Whh1*h1_prev + Wih1*h0_new + bias
__device__ __forceinline__ void phaseL1(int wv, int b0, int col, int quad, int u, int bq,
    const uint16_t* h1c, const uint16_t* h0n, uint16_t* h1n, float* c1,
    const uint16_t* Whh1, const uint16_t* Wih1, const float* b1)
{
  if (wv >= 512) return;
  fx4 acc[4];
  #pragma unroll
  for (int g = 0; g < 4; ++g){
    float bb = b1[(g << 9) + u];
    #pragma unroll
    for (int r = 0; r < 4; ++r) acc[g][r] = bb;
  }
  accK512(acc, h1c + (b0 + col)*512 + quad*8,
          Whh1 + ((size_t)(0*512 + u))*512 + quad*8,
          Whh1 + ((size_t)(1*512 + u))*512 + quad*8,
          Whh1 + ((size_t)(2*512 + u))*512 + quad*8,
          Whh1 + ((size_t)(3*512 + u))*512 + quad*8);
  accK512(acc, h0n + (b0 + col)*512 + quad*8,
          Wih1 + ((size_t)(0*512 + u))*512 + quad*8,
          Wih1 + ((size_t)(1*512 + u))*512 + quad*8,
          Wih1 + ((size_t)(2*512 + u))*512 + quad*8,
          Wih1 + ((size_t)(3*512 + u))*512 + quad*8);
  pointwise(acc, bq, u, c1, h1n);
}

__global__ void __launch_bounds__(NTHR)
seq2seq_main(const uint16_t* __restrict__ Whh0e, const uint16_t* __restrict__ Wih1e,
             const uint16_t* __restrict__ Whh1e, const uint16_t* __restrict__ Whh0d,
             const uint16_t* __restrict__ Wih1d, const uint16_t* __restrict__ Whh1d,
             const uint16_t* __restrict__ Wy,
             const float* __restrict__ E0e, const float* __restrict__ E0d,
             const float* __restrict__ b1e, const float* __restrict__ b1d,
             const float* __restrict__ wcol0,
             uint16_t* h0buf, uint16_t* h1buf, float* c0, float* c1,
             const float* __restrict__ xh, const float* __restrict__ xf,
             const float* __restrict__ y0v,
             const float* __restrict__ encWih0, const float* __restrict__ decWih0,
             const float* __restrict__ projW, const float* __restrict__ projB,
             float* out, unsigned* bar)
{
  const int tid  = threadIdx.x;
  const int lane = tid & 63;
  const int wv   = (tid >> 6) * NBLK + blockIdx.x;   // interleave waves across CUs
  const int col  = lane & 15;
  const int quad = lane >> 4;
  const int mb = wv >> 5, ub = wv & 31;
  const int b0 = mb << 4, u0 = ub << 4;
  const int u  = u0 + col;
  const int bq = b0 + (quad << 2);
  unsigned gen = 0;
  int p = 0;

  // ----------------- encoder -----------------
  #pragma unroll 1
  for (int t = 0; t < 288; ++t){
    if (wv < 512){   // layer 0
      fx4 acc[4];
      #pragma unroll
      for (int g = 0; g < 4; ++g){
        int j = (g << 9) + u;
        #pragma unroll
        for (int r = 0; r < 4; ++r) acc[g][r] = E0e[(size_t)(bq + r)*2048 + j];
      }
      accK512(acc, h0buf + p*BH + (b0 + col)*512 + quad*8,
              Whh0e + ((size_t)(0*512 + u))*512 + quad*8,
              Whh0e + ((size_t)(1*512 + u))*512 + quad*8,
              Whh0e + ((size_t)(2*512 + u))*512 + quad*8,
              Whh0e + ((size_t)(3*512 + u))*512 + quad*8);
      float xv[4][8];
      #pragma unroll
      for (int r = 0; r < 4; ++r){
        const float* xr = xh + ((size_t)(bq + r)*288 + t)*8;
        #pragma unroll
        for (int k = 0; k < 8; ++k) xv[r][k] = xr[k];
      }
      #pragma unroll
      for (int g = 0; g < 4; ++g){
        const float* wr = encWih0 + (size_t)((g << 9) + u)*24;
        #pragma unroll
        for (int k = 0; k < 8; ++k){
          float w = wr[k];
          #pragma unroll
          for (int r = 0; r < 4; ++r) acc[g][r] += w * xv[r][k];
        }
      }
      pointwise(acc, bq, u, c0, h0buf + (p^1)*BH);
    }
    gridbar(bar, ++gen);
    phaseL1(wv, b0, col, quad, u, bq,
            h1buf + p*BH, h0buf + (p^1)*BH, h1buf + (p^1)*BH, c1,
            Whh1e, Wih1e, b1e);
    gridbar(bar, ++gen);
    p ^= 1;
  }

  // ----------------- decoder -----------------
  #pragma unroll 1
  for (int t = 0; t < 288; ++t){
    if (wv < 512){   // layer 0 (y folded in as rank-1 Wy @ h1_prev)
      fx4 acc[4];
      #pragma unroll
      for (int g = 0; g < 4; ++g){
        int j = (g << 9) + u;
        #pragma unroll
        for (int r = 0; r < 4; ++r) acc[g][r] = E0d[(size_t)(bq + r)*2048 + j];
      }
      accK512(acc, h0buf + p*BH + (b0 + col)*512 + quad*8,
              Whh0d + ((size_t)(0*512 + u))*512 + quad*8,
              Whh0d + ((size_t)(1*512 + u))*512 + quad*8,
              Whh0d + ((size_t)(2*512 + u))*512 + quad*8,
              Whh0d + ((size_t)(3*512 + u))*512 + quad*8);
      if (t > 0)
        accK512(acc, h1buf + p*BH + (b0 + col)*512 + quad*8,
                Wy + ((size_t)(0*512 + u))*512 + quad*8,
                Wy + ((size_t)(1*512 + u))*512 + quad*8,
                Wy + ((size_t)(2*512 + u))*512 + quad*8,
                Wy + ((size_t)(3*512 + u))*512 + quad*8);
      float s[4];
      #pragma unroll
      for (int r = 0; r < 4; ++r) s[r] = (t == 0) ? y0v[bq + r] : projB[0];
      #pragma unroll
      for (int g = 0; g < 4; ++g){
        float w = wcol0[(g << 9) + u];
        #pragma unroll
        for (int r = 0; r < 4; ++r) acc[g][r] += w * s[r];
      }
      float xv[4][6];
      #pragma unroll
      for (int r = 0; r < 4; ++r){
        const float* xr = xf + ((size_t)(bq + r)*288 + t)*6;
        #pragma unroll
        for (int k = 0; k < 6; ++k) xv[r][k] = xr[k];
      }
      #pragma unroll
      for (int g = 0; g < 4; ++g){
        const float* wr = decWih0 + (size_t)((g << 9) + u)*23 + 1;
        #pragma unroll
        for (int k = 0; k < 6; ++k){
          float w = wr[k];
          #pragma unroll
          for (int r = 0; r < 4; ++r) acc[g][r] += w * xv[r][k];
        }
      }
      pointwise(acc, bq, u, c0, h0buf + (p^1)*BH);
    } else if (wv < 768 && t > 0){
      // idle waves: emit y_{t-1} = proj(h1_{t-1}) + b  (one wave per batch row)
      int b = wv - 512;
      const uint16_t* hr = h1buf + p*BH + b*512 + lane*8;
      const float* pw = projW + lane*8;
      float part = 0.f;
      #pragma unroll
      for (int k = 0; k < 8; ++k) part += bf2f(hr[k]) * pw[k];
      #pragma unroll
      for (int off = 32; off > 0; off >>= 1) part += __shfl_down(part, off);
      if (lane == 0) out[(size_t)b*288 + (t - 1)] = part + projB[0];
    }
    gridbar(bar, ++gen);
    phaseL1(wv, b0, col, quad, u, bq,
            h1buf + p*BH, h0buf + (p^1)*BH, h1buf + (p^1)*BH, c1,
            Whh1d, Wih1d, b1d);
    gridbar(bar, ++gen);
    p ^= 1;
  }

  // final y_287
  if (wv < 256){
    int b = wv;
    const uint16_t* hr = h1buf + p*BH + b*512 + lane*8;
    const float* pw = projW + lane*8;
    float part = 0.f;
    #pragma unroll
    for (int k = 0; k < 8; ++k) part += bf2f(hr[k]) * pw[k];
    #pragma unroll
    for (int off = 32; off > 0; off >>= 1) part += __shfl_down(part, off);
    if (lane == 0) out[(size_t)b*288 + 287] = part + projB[0];
  }
}

// ---------------- prep: bf16 weights, Wy fold, emb+bias fold ----------------
#define PREP_S 1048576
#define PREP_TOTAL (8*PREP_S + 6144)

__global__ void __launch_bounds__(256)
prep_kernel(const float* __restrict__ encWih0, const float* __restrict__ encWhh0,
            const float* __restrict__ encWih1, const float* __restrict__ encWhh1,
            const float* __restrict__ decWih0, const float* __restrict__ decWhh0,
            const float* __restrict__ decWih1, const float* __restrict__ decWhh1,
            const float* __restrict__ encbih0, const float* __restrict__ encbhh0,
            const float* __restrict__ encbih1, const float* __restrict__ encbhh1,
            const float* __restrict__ decbih0, const float* __restrict__ decbhh0,
            const float* __restrict__ decbih1, const float* __restrict__ decbhh1,
            const float* __restrict__ projW, const float* __restrict__ emb,
            const int* __restrict__ turb,
            uint16_t* Whh0e, uint16_t* Wih1e, uint16_t* Whh1e,
            uint16_t* Whh0d, uint16_t* Wih1d, uint16_t* Whh1d, uint16_t* Wy,
            float* E0e, float* E0d, float* b1e, float* b1d, float* wcol0)
{
  int i = blockIdx.x*256 + threadIdx.x;
  if (i >= PREP_TOTAL) return;
  if (i < 6*PREP_S){
    int w = i >> 20, r = i & (PREP_S - 1);
    const float* src = (w==0)?encWhh0:(w==1)?encWih1:(w==2)?encWhh1:
                       (w==3)?decWhh0:(w==4)?decWih1:decWhh1;
    uint16_t* dst = (w==0)?Whh0e:(w==1)?Wih1e:(w==2)?Whh1e:
                    (w==3)?Whh0d:(w==4)?Wih1d:Whh1d;
    dst[r] = f2bf(src[r]);
  } else if (i < 7*PREP_S){
    int r = i - 6*PREP_S; int j = r >> 9, k = r & 511;
    Wy[r] = f2bf(decWih0[(size_t)j*23] * projW[k]);
  } else if (i < 7*PREP_S + 524288){
    int r = i - 7*PREP_S; int b = r >> 11, j = r & 2047;
    float s = encbih0[j] + encbhh0[j];
    const float* e = emb + (size_t)turb[b]*16;
    const float* wr = encWih0 + (size_t)j*24 + 8;
    #pragma unroll
    for (int m = 0; m < 16; ++m) s += e[m]*wr[m];
    E0e[r] = s;
  } else if (i < 8*PREP_S){
    int r = i - 7*PREP_S - 524288; int b = r >> 11, j = r & 2047;
    float s = decbih0[j] + decbhh0[j];
    const float* e = emb + (size_t)turb[b]*16;
    const float* wr = decWih0 + (size_t)j*23 + 7;
    #pragma unroll
    for (int m = 0; m < 16; ++m) s += e[m]*wr[m];
    E0d[r] = s;
  } else {
    int r = i - 8*PREP_S;
    if (r < 2048)      b1e[r] = encbih1[r] + encbhh1[r];
    else if (r < 4096){ int j = r - 2048; b1d[j] = decbih1[j] + decbhh1[j]; }
    else              { int j = r - 4096; wcol0[j] = decWih0[(size_t)j*23]; }
  }
}

// ---------------------------------------------------------------------------
extern "C" void kernel_launch(void* const* d_in, const int* in_sizes, int n_in,
                              void* d_out, int out_size, void* d_ws, size_t ws_size,
                              hipStream_t stream)
{
  const float* xh      = (const float*)d_in[0];
  const float* xf      = (const float*)d_in[1];
  const float* y0v     = (const float*)d_in[2];
  const int*   turb    = (const int*)d_in[3];
  const float* emb     = (const float*)d_in[5];
  const float* encWih0 = (const float*)d_in[6];
  const float* encWhh0 = (const float*)d_in[7];
  const float* encbih0 = (const float*)d_in[8];
  const float* encbhh0 = (const float*)d_in[9];
  const float* encWih1 = (const float*)d_in[10];
  const float* encWhh1 = (const float*)d_in[11];
  const float* encbih1 = (const float*)d_in[12];
  const float* encbhh1 = (const float*)d_in[13];
  const float* decWih0 = (const float*)d_in[14];
  const float* decWhh0 = (const float*)d_in[15];
  const float* decbih0 = (const float*)d_in[16];
  const float* decbhh0 = (const float*)d_in[17];
  const float* decWih1 = (const float*)d_in[18];
  const float* decWhh1 = (const float*)d_in[19];
  const float* decbih1 = (const float*)d_in[20];
  const float* decbhh1 = (const float*)d_in[21];
  const float* projW   = (const float*)d_in[22];
  const float* projB   = (const float*)d_in[23];
  float* out = (float*)d_out;

  char* ws = (char*)d_ws;
  constexpr size_t SZW = (size_t)2048*512*2;
  constexpr size_t OFF_Whh0e = 0;
  constexpr size_t OFF_Wih1e = SZW;
  constexpr size_t OFF_Whh1e = 2*SZW;
  constexpr size_t OFF_Whh0d = 3*SZW;
  constexpr size_t OFF_Wih1d = 4*SZW;
  constexpr size_t OFF_Whh1d = 5*SZW;
  constexpr size_t OFF_Wy    = 6*SZW;
  constexpr size_t OFF_E0e   = 7*SZW;
  constexpr size_t OFF_E0d   = OFF_E0e + 2097152;
  constexpr size_t OFF_b1e   = OFF_E0d + 2097152;
  constexpr size_t OFF_b1d   = OFF_b1e + 8192;
  constexpr size_t OFF_wcol0 = OFF_b1d + 8192;
  constexpr size_t OFF_h0    = OFF_wcol0 + 8192;
  constexpr size_t OFF_h1    = OFF_h0 + 524288;
  constexpr size_t OFF_c0    = OFF_h1 + 524288;
  constexpr size_t OFF_c1    = OFF_c0 + 524288;
  constexpr size_t OFF_bar   = OFF_c1 + 524288;
  constexpr size_t ZERO_BYTES = 4*524288 + 16704;   // h0,h1,c0,c1 + barrier

  uint16_t* Whh0e = (uint16_t*)(ws + OFF_Whh0e);
  uint16_t* Wih1e = (uint16_t*)(ws + OFF_Wih1e);
  uint16_t* Whh1e = (uint16_t*)(ws + OFF_Whh1e);
  uint16_t* Whh0d = (uint16_t*)(ws + OFF_Whh0d);
  uint16_t* Wih1d = (uint16_t*)(ws + OFF_Wih1d);
  uint16_t* Whh1d = (uint16_t*)(ws + OFF_Whh1d);
  uint16_t* Wyp   = (uint16_t*)(ws + OFF_Wy);
  float* E0e   = (float*)(ws + OFF_E0e);
  float* E0d   = (float*)(ws + OFF_E0d);
  float* b1e   = (float*)(ws + OFF_b1e);
  float* b1d   = (float*)(ws + OFF_b1d);
  float* wcol0 = (float*)(ws + OFF_wcol0);
  uint16_t* h0p = (uint16_t*)(ws + OFF_h0);
  uint16_t* h1p = (uint16_t*)(ws + OFF_h1);
  float* c0p = (float*)(ws + OFF_c0);
  float* c1p = (float*)(ws + OFF_c1);
  unsigned* barp = (unsigned*)(ws + OFF_bar);

  hipMemsetAsync(ws + OFF_h0, 0, ZERO_BYTES, stream);

  prep_kernel<<<dim3((PREP_TOTAL + 255)/256), dim3(256), 0, stream>>>(
      encWih0, encWhh0, encWih1, encWhh1, decWih0, decWhh0, decWih1, decWhh1,
      encbih0, encbhh0, encbih1, encbhh1, decbih0, decbhh0, decbih1, decbhh1,
      projW, emb, turb,
      Whh0e, Wih1e, Whh1e, Whh0d, Wih1d, Whh1d, Wyp,
      E0e, E0d, b1e, b1d, wcol0);

  const uint16_t* cWhh0e = Whh0e; const uint16_t* cWih1e = Wih1e;
  const uint16_t* cWhh1e = Whh1e; const uint16_t* cWhh0d = Whh0d;
  const uint16_t* cWih1d = Wih1d; const uint16_t* cWhh1d = Whh1d;
  const uint16_t* cWy = Wyp;
  const float* cE0e = E0e; const float* cE0d = E0d;
  const float* cb1e = b1e; const float* cb1d = b1d; const float* cwcol0 = wcol0;

  void* kargs[] = {
    (void*)&cWhh0e, (void*)&cWih1e, (void*)&cWhh1e, (void*)&cWhh0d,
    (void*)&cWih1d, (void*)&cWhh1d, (void*)&cWy,
    (void*)&cE0e, (void*)&cE0d, (void*)&cb1e, (void*)&cb1d, (void*)&cwcol0,
    (void*)&h0p, (void*)&h1p, (void*)&c0p, (void*)&c1p,
    (void*)&xh, (void*)&xf, (void*)&y0v,
    (void*)&encWih0, (void*)&decWih0, (void*)&projW, (void*)&projB,
    (void*)&out, (void*)&barp
  };
  hipLaunchCooperativeKernel((void*)seq2seq_main, dim3(NBLK), dim3(NTHR),
                             kargs, 0, stream);
}

// Round 4
// 23897.603 us; speedup vs baseline: 1.9911x; 1.9911x over previous
//
#include <hip/hip_runtime.h>
#include <stdint.h>

// ---------------------------------------------------------------------------
// Seq2Seq LSTM (2-layer enc + 2-layer autoregressive dec), B=256,H=512,T=288.
// Cooperative persistent kernel; bf16 MFMA 16x16x32 w/ fp32 accum.
// R4 = R1 chassis (proven correct: rel/acq h publication, 2 bars/step,
// wave-parallel L0/L1) with two surgical changes:
//   1. barrier: single counter; arrival=fetch_add RELEASE (1 wbL2/block),
//      poll=fetch_add(0) RELAXED (RMW at coherence point, NO cache ops),
//      exit=1 acquire load (1 buffer_inv/block). Kills the per-poll
//      L2-invalidate storm that made R1 38.5us/phase.
//   2. c0/c1 live in registers (wave-private) - removes ~1MB/phase wb+fetch.
// ---------------------------------------------------------------------------

typedef __attribute__((ext_vector_type(8))) short bfx8;   // 8 bf16 (4 VGPRs)
typedef __attribute__((ext_vector_type(4))) float fx4;

#define NBLK 256
#define NTHR 256
#define BH   (256*512)

__device__ __forceinline__ unsigned short f2bf(float f){
  unsigned u = __float_as_uint(f);
  u += 0x7FFFu + ((u >> 16) & 1u);          // RNE
  return (unsigned short)(u >> 16);
}
__device__ __forceinline__ float bf2f(unsigned short b){
  return __uint_as_float(((unsigned)b) << 16);
}
__device__ __forceinline__ float sigm(float x){ return 1.0f/(1.0f + __expf(-x)); }
__device__ __forceinline__ float tanhf_(float x){
  x = fminf(12.0f, fmaxf(-12.0f, x));
  float e = __expf(2.0f*x);
  return (e - 1.0f)/(e + 1.0f);
}

// Grid barrier: single monotone counter.
// Arrival: atomic add w/ RELEASE (drains vmem + wbL2 once, publishes h).
// Poll: atomic add-0 (RMW -> serviced at coherence point, always fresh,
//       no cache-maintenance per iteration).
// Exit: one ACQUIRE load (buffer_inv once) so subsequent plain h loads miss
//       stale L2/L1 lines. Same semantics as R1's proven barrier, ~1000x
//       fewer cache ops.
__device__ __forceinline__ void gridbar(unsigned* cnt, unsigned target){
  __syncthreads();   // compiler emits s_waitcnt vmcnt(0) before s_barrier
  if (threadIdx.x == 0){
    __hip_atomic_fetch_add(cnt, 1u, __ATOMIC_RELEASE, __HIP_MEMORY_SCOPE_AGENT);
    while (__hip_atomic_fetch_add(cnt, 0u, __ATOMIC_RELAXED,
                                  __HIP_MEMORY_SCOPE_AGENT) < target)
      __builtin_amdgcn_s_sleep(4);
    (void)__hip_atomic_load(cnt, __ATOMIC_ACQUIRE, __HIP_MEMORY_SCOPE_AGENT);
  }
  __syncthreads();
}

// Accumulate K=512: A rows from h (bf16), 4 gate columns of W ([2048][512] bf16).
__device__ __forceinline__ void accK512(fx4* acc, const uint16_t* aq,
                                        const uint16_t* w0, const uint16_t* w1,
                                        const uint16_t* w2, const uint16_t* w3){
  #pragma unroll
  for (int kc = 0; kc < 16; ++kc){
    bfx8 af = *(const bfx8*)(aq + kc*32);
    acc[0] = __builtin_amdgcn_mfma_f32_16x16x32_bf16(af, *(const bfx8*)(w0 + kc*32), acc[0], 0, 0, 0);
    acc[1] = __builtin_amdgcn_mfma_f32_16x16x32_bf16(af, *(const bfx8*)(w1 + kc*32), acc[1], 0, 0, 0);
    acc[2] = __builtin_amdgcn_mfma_f32_16x16x32_bf16(af, *(const bfx8*)(w2 + kc*32), acc[2], 0, 0, 0);
    acc[3] = __builtin_amdgcn_mfma_f32_16x16x32_bf16(af, *(const bfx8*)(w3 + kc*32), acc[3], 0, 0, 0);
  }
}

// LSTM pointwise: c in registers (wave-private), h store to global.
__device__ __forceinline__ void pointwise(fx4* acc, fx4& creg, int bq, int u,
                                          uint16_t* hout){
  #pragma unroll
  for (int r = 0; r < 4; ++r){
    int b = bq + r;
    float iv = sigm(acc[0][r]);
    float fv = sigm(acc[1][r]);
    float gv = tanhf_(acc[2][r]);
    float ov = sigm(acc[3][r]);
    float cn = fv * creg[r] + iv * gv;
    creg[r] = cn;
    hout[b*512 + u] = f2bf(ov * tanhf_(cn));
  }
}

// Layer-1 phase (shared enc/dec): g1 = Whh1*h1_prev + Wih1*h0_new + bias
__device__ __forceinline__ void phaseL1(int wv, int b0, int col, int quad, int u, int bq,
    const uint16_t* h1c, const uint16_t* h0n, uint16_t* h1n, fx4& c1reg,
    const uint16_t* Whh1, const uint16_t* Wih1, const float* b1)
{
  if (wv >= 512) return;
  fx4 acc[4];
  #pragma unroll
  for (int g = 0; g < 4; ++g){
    float bb = b1[(g << 9) + u];
    #pragma unroll
    for (int r = 0; r < 4; ++r) acc[g][r] = bb;
  }
  accK512(acc, h1c + (b0 + col)*512 + quad*8,
          Whh1 + ((size_t)(0*512 + u))*512 + quad*8,
          Whh1 + ((size_t)(1*512 + u))*512 + quad*8,
          Whh1 + ((size_t)(2*512 + u))*512 + quad*8,
          Whh1 + ((size_t)(3*512 + u))*512 + quad*8);
  accK512(acc, h0n + (b0 + col)*512 + quad*8,
          Wih1 + ((size_t)(0*512 + u))*512 + quad*8,
          Wih1 + ((size_t)(1*512 + u))*512 + quad*8,
          Wih1 + ((size_t)(2*512 + u))*512 + quad*8,
          Wih1 + ((size_t)(3*512 + u))*512 + quad*8);
  pointwise(acc, c1reg, bq, u, h1n);
}

__global__ void __launch_bounds__(NTHR)
seq2seq_main(const uint16_t* __restrict__ Whh0e, const uint16_t* __restrict__ Wih1e,
             const uint16_t* __restrict__ Whh1e, const uint16_t* __restrict__ Whh0d,
             const uint16_t* __restrict__ Wih1d, const uint16_t* __restrict__ Whh1d,
             const uint16_t* __restrict__ Wy,
             const float* __restrict__ E0e, const float* __restrict__ E0d,
             const float* __restrict__ b1e, const float* __restrict__ b1d,
             const float* __restrict__ wcol0,
             uint16_t* h0buf, uint16_t* h1buf,
             const float* __restrict__ xh, const float* __restrict__ xf,
             const float* __restrict__ y0v,
             const float* __restrict__ encWih0, const float* __restrict__ decWih0,
             const float* __restrict__ projW, const float* __restrict__ projB,
             float* out, unsigned* cnt)
{
  const int tid  = threadIdx.x;
  const int lane = tid & 63;
  const int wv   = (tid >> 6) * NBLK + blockIdx.x;   // interleave waves across CUs
  const int col  = lane & 15;
  const int quad = lane >> 4;
  const int mb = wv >> 5, ub = wv & 31;
  const int b0 = mb << 4, u0 = ub << 4;
  const int u  = u0 + col;
  const int bq = b0 + (quad << 2);
  unsigned gen = 0;
  int p = 0;
  fx4 c0reg = {0.f,0.f,0.f,0.f};
  fx4 c1reg = {0.f,0.f,0.f,0.f};

  // ----------------- encoder -----------------
  #pragma unroll 1
  for (int t = 0; t < 288; ++t){
    if (wv < 512){   // layer 0
      fx4 acc[4];
      #pragma unroll
      for (int g = 0; g < 4; ++g){
        int j = (g << 9) + u;
        #pragma unroll
        for (int r = 0; r < 4; ++r) acc[g][r] = E0e[(size_t)(bq + r)*2048 + j];
      }
      accK512(acc, h0buf + p*BH + (b0 + col)*512 + quad*8,
              Whh0e + ((size_t)(0*512 + u))*512 + quad*8,
              Whh0e + ((size_t)(1*512 + u))*512 + quad*8,
              Whh0e + ((size_t)(2*512 + u))*512 + quad*8,
              Whh0e + ((size_t)(3*512 + u))*512 + quad*8);
      float xv[4][8];
      #pragma unroll
      for (int r = 0; r < 4; ++r){
        const float* xr = xh + ((size_t)(bq + r)*288 + t)*8;
        #pragma unroll
        for (int k = 0; k < 8; ++k) xv[r][k] = xr[k];
      }
      #pragma unroll
      for (int g = 0; g < 4; ++g){
        const float* wr = encWih0 + (size_t)((g << 9) + u)*24;
        #pragma unroll
        for (int k = 0; k < 8; ++k){
          float w = wr[k];
          #pragma unroll
          for (int r = 0; r < 4; ++r) acc[g][r] += w * xv[r][k];
        }
      }
      pointwise(acc, c0reg, bq, u, h0buf + (p^1)*BH);
    }
    gridbar(cnt, (++gen)*NBLK);
    phaseL1(wv, b0, col, quad, u, bq,
            h1buf + p*BH, h0buf + (p^1)*BH, h1buf + (p^1)*BH, c1reg,
            Whh1e, Wih1e, b1e);
    gridbar(cnt, (++gen)*NBLK);
    p ^= 1;
  }

  // ----------------- decoder -----------------
  #pragma unroll 1
  for (int t = 0; t < 288; ++t){
    if (wv < 512){   // layer 0 (y folded in as rank-1 Wy @ h1_prev)
      fx4 acc[4];
      #pragma unroll
      for (int g = 0; g < 4; ++g){
        int j = (g << 9) + u;
        #pragma unroll
        for (int r = 0; r < 4; ++r) acc[g][r] = E0d[(size_t)(bq + r)*2048 + j];
      }
      accK512(acc, h0buf + p*BH + (b0 + col)*512 + quad*8,
              Whh0d + ((size_t)(0*512 + u))*512 + quad*8,
              Whh0d + ((size_t)(1*512 + u))*512 + quad*8,
              Whh0d + ((size_t)(2*512 + u))*512 + quad*8,
              Whh0d + ((size_t)(3*512 + u))*512 + quad*8);
      if (t > 0)
        accK512(acc, h1buf + p*BH + (b0 + col)*512 + quad*8,
                Wy + ((size_t)(0*512 + u))*512 + quad*8,
                Wy + ((size_t)(1*512 + u))*512 + quad*8,
                Wy + ((size_t)(2*512 + u))*512 + quad*8,
                Wy + ((size_t)(3*512 + u))*512 + quad*8);
      float s[4];
      #pragma unroll
      for (int r = 0; r < 4; ++r) s[r] = (t == 0) ? y0v[bq + r] : projB[0];
      #pragma unroll
      for (int g = 0; g < 4; ++g){
        float w = wcol0[(g << 9) + u];
        #pragma unroll
        for (int r = 0; r < 4; ++r) acc[g][r] += w * s[r];
      }
      float xv[4][6];
      #pragma unroll
      for (int r = 0; r < 4; ++r){
        const float* xr = xf + ((size_t)(bq + r)*288 + t)*6;
        #pragma unroll
        for (int k = 0; k < 6; ++k) xv[r][k] = xr[k];
      }
      #pragma unroll
      for (int g = 0; g < 4; ++g){
        const float* wr = decWih0 + (size_t)((g << 9) + u)*23 + 1;
        #pragma unroll
        for (int k = 0; k < 6; ++k){
          float w = wr[k];
          #pragma unroll
          for (int r = 0; r < 4; ++r) acc[g][r] += w * xv[r][k];
        }
      }
      pointwise(acc, c0reg, bq, u, h0buf + (p^1)*BH);
    } else if (wv < 768 && t > 0){
      // idle waves: emit y_{t-1} = proj(h1_{t-1}) + b  (one wave per batch row)
      int b = wv - 512;
      const uint16_t* hr = h1buf + p*BH + b*512 + lane*8;
      const float* pw = projW + lane*8;
      float part = 0.f;
      #pragma unroll
      for (int k = 0; k < 8; ++k) part += bf2f(hr[k]) * pw[k];
      #pragma unroll
      for (int off = 32; off > 0; off >>= 1) part += __shfl_down(part, off);
      if (lane == 0) out[(size_t)b*288 + (t - 1)] = part + projB[0];
    }
    gridbar(cnt, (++gen)*NBLK);
    phaseL1(wv, b0, col, quad, u, bq,
            h1buf + p*BH, h0buf + (p^1)*BH, h1buf + (p^1)*BH, c1reg,
            Whh1d, Wih1d, b1d);
    gridbar(cnt, (++gen)*NBLK);
    p ^= 1;
  }

  // final y_287
  if (wv < 256){
    int b = wv;
    const uint16_t* hr = h1buf + p*BH + b*512 + lane*8;
    const float* pw = projW + lane*8;
    float part = 0.f;
    #pragma unroll
    for (int k = 0; k < 8; ++k) part += bf2f(hr[k]) * pw[k];
    #pragma unroll
    for (int off = 32; off > 0; off >>= 1) part += __shfl_down(part, off);
    if (lane == 0) out[(size_t)b*288 + 287] = part + projB[0];
  }
}

// ---------------- prep: bf16 weights, Wy fold, emb+bias fold ----------------
#define PREP_S 1048576
#define PREP_TOTAL (8*PREP_S + 6144)

__global__ void __launch_bounds__(256)
prep_kernel(const float* __restrict__ encWih0, const float* __restrict__ encWhh0,
            const float* __restrict__ encWih1, const float* __restrict__ encWhh1,
            const float* __restrict__ decWih0, const float* __restrict__ decWhh0,
            const float* __restrict__ decWih1, const float* __restrict__ decWhh1,
            const float* __restrict__ encbih0, const float* __restrict__ encbhh0,
            const float* __restrict__ encbih1, const float* __restrict__ encbhh1,
            const float* __restrict__ decbih0, const float* __restrict__ decbhh0,
            const float* __restrict__ decbih1, const float* __restrict__ decbhh1,
            const float* __restrict__ projW, const float* __restrict__ emb,
            const int* __restrict__ turb,
            uint16_t* Whh0e, uint16_t* Wih1e, uint16_t* Whh1e,
            uint16_t* Whh0d, uint16_t* Wih1d, uint16_t* Whh1d, uint16_t* Wy,
            float* E0e, float* E0d, float* b1e, float* b1d, float* wcol0)
{
  int i = blockIdx.x*256 + threadIdx.x;
  if (i >= PREP_TOTAL) return;
  if (i < 6*PREP_S){
    int w = i >> 20, r = i & (PREP_S - 1);
    const float* src = (w==0)?encWhh0:(w==1)?encWih1:(w==2)?encWhh1:
                       (w==3)?decWhh0:(w==4)?decWih1:decWhh1;
    uint16_t* dst = (w==0)?Whh0e:(w==1)?Wih1e:(w==2)?Whh1e:
                    (w==3)?Whh0d:(w==4)?Wih1d:Whh1d;
    dst[r] = f2bf(src[r]);
  } else if (i < 7*PREP_S){
    int r = i - 6*PREP_S; int j = r >> 9, k = r & 511;
    Wy[r] = f2bf(decWih0[(size_t)j*23] * projW[k]);
  } else if (i < 7*PREP_S + 524288){
    int r = i - 7*PREP_S; int b = r >> 11, j = r & 2047;
    float s = encbih0[j] + encbhh0[j];
    const float* e = emb + (size_t)turb[b]*16;
    const float* wr = encWih0 + (size_t)j*24 + 8;
    #pragma unroll
    for (int m = 0; m < 16; ++m) s += e[m]*wr[m];
    E0e[r] = s;
  } else if (i < 8*PREP_S){
    int r = i - 7*PREP_S - 524288; int b = r >> 11, j = r & 2047;
    float s = decbih0[j] + decbhh0[j];
    const float* e = emb + (size_t)turb[b]*16;
    const float* wr = decWih0 + (size_t)j*23 + 7;
    #pragma unroll
    for (int m = 0; m < 16; ++m) s += e[m]*wr[m];
    E0d[r] = s;
  } else {
    int r = i - 8*PREP_S;
    if (r < 2048)      b1e[r] = encbih1[r] + encbhh1[r];
    else if (r < 4096){ int j = r - 2048; b1d[j] = decbih1[j] + decbhh1[j]; }
    else              { int j = r - 4096; wcol0[j] = decWih0[(size_t)j*23]; }
  }
}

// ---------------------------------------------------------------------------
extern "C" void kernel_launch(void* const* d_in, const int* in_sizes, int n_in,
                              void* d_out, int out_size, void* d_ws, size_t ws_size,
                              hipStream_t stream)
{
  const float* xh      = (const float*)d_in[0];
  const float* xf      = (const float*)d_in[1];
  const float* y0v     = (const float*)d_in[2];
  const int*   turb    = (const int*)d_in[3];
  const float* emb     = (const float*)d_in[5];
  const float* encWih0 = (const float*)d_in[6];
  const float* encWhh0 = (const float*)d_in[7];
  const float* encbih0 = (const float*)d_in[8];
  const float* encbhh0 = (const float*)d_in[9];
  const float* encWih1 = (const float*)d_in[10];
  const float* encWhh1 = (const float*)d_in[11];
  const float* encbih1 = (const float*)d_in[12];
  const float* encbhh1 = (const float*)d_in[13];
  const float* decWih0 = (const float*)d_in[14];
  const float* decWhh0 = (const float*)d_in[15];
  const float* decbih0 = (const float*)d_in[16];
  const float* decbhh0 = (const float*)d_in[17];
  const float* decWih1 = (const float*)d_in[18];
  const float* decWhh1 = (const float*)d_in[19];
  const float* decbih1 = (const float*)d_in[20];
  const float* decbhh1 = (const float*)d_in[21];
  const float* projW   = (const float*)d_in[22];
  const float* projB   = (const float*)d_in[23];
  float* out = (float*)d_out;

  char* ws = (char*)d_ws;
  constexpr size_t SZW = (size_t)2048*512*2;
  constexpr size_t OFF_Whh0e = 0;
  constexpr size_t OFF_Wih1e = SZW;
  constexpr size_t OFF_Whh1e = 2*SZW;
  constexpr size_t OFF_Whh0d = 3*SZW;
  constexpr size_t OFF_Wih1d = 4*SZW;
  constexpr size_t OFF_Whh1d = 5*SZW;
  constexpr size_t OFF_Wy    = 6*SZW;
  constexpr size_t OFF_E0e   = 7*SZW;
  constexpr size_t OFF_E0d   = OFF_E0e + 2097152;
  constexpr size_t OFF_b1e   = OFF_E0d + 2097152;
  constexpr size_t OFF_b1d   = OFF_b1e + 8192;
  constexpr size_t OFF_wcol0 = OFF_b1d + 8192;
  constexpr size_t OFF_h0    = OFF_wcol0 + 8192;
  constexpr size_t OFF_h1    = OFF_h0 + 524288;
  constexpr size_t OFF_cnt   = OFF_h1 + 524288;
  constexpr size_t ZERO_BYTES = 2*524288 + 64;   // h0,h1 ping-pong + counter

  uint16_t* Whh0e = (uint16_t*)(ws + OFF_Whh0e);
  uint16_t* Wih1e = (uint16_t*)(ws + OFF_Wih1e);
  uint16_t* Whh1e = (uint16_t*)(ws + OFF_Whh1e);
  uint16_t* Whh0d = (uint16_t*)(ws + OFF_Whh0d);
  uint16_t* Wih1d = (uint16_t*)(ws + OFF_Wih1d);
  uint16_t* Whh1d = (uint16_t*)(ws + OFF_Whh1d);
  uint16_t* Wyp   = (uint16_t*)(ws + OFF_Wy);
  float* E0e   = (float*)(ws + OFF_E0e);
  float* E0d   = (float*)(ws + OFF_E0d);
  float* b1e   = (float*)(ws + OFF_b1e);
  float* b1d   = (float*)(ws + OFF_b1d);
  float* wcol0 = (float*)(ws + OFF_wcol0);
  uint16_t* h0p = (uint16_t*)(ws + OFF_h0);
  uint16_t* h1p = (uint16_t*)(ws + OFF_h1);
  unsigned* cntp = (unsigned*)(ws + OFF_cnt);

  hipMemsetAsync(ws + OFF_h0, 0, ZERO_BYTES, stream);

  prep_kernel<<<dim3((PREP_TOTAL + 255)/256), dim3(256), 0, stream>>>(
      encWih0, encWhh0, encWih1, encWhh1, decWih0, decWhh0, decWih1, decWhh1,
      encbih0, encbhh0, encbih1, encbhh1, decbih0, decbhh0, decbih1, decbhh1,
      projW, emb, turb,
      Whh0e, Wih1e, Whh1e, Whh0d, Wih1d, Whh1d, Wyp,
      E0e, E0d, b1e, b1d, wcol0);

  const uint16_t* cWhh0e = Whh0e; const uint16_t* cWih1e = Wih1e;
  const uint16_t* cWhh1e = Whh1e; const uint16_t* cWhh0d = Whh0d;
  const uint16_t* cWih1d = Wih1d; const uint16_t* cWhh1d = Whh1d;
  const uint16_t* cWy = Wyp;
  const float* cE0e = E0e; const float* cE0d = E0d;
  const float* cb1e = b1e; const float* cb1d = b1d; const float* cwcol0 = wcol0;

  void* kargs[] = {
    (void*)&cWhh0e, (void*)&cWih1e, (void*)&cWhh1e, (void*)&cWhh0d,
    (void*)&cWih1d, (void*)&cWhh1d, (void*)&cWy,
    (void*)&cE0e, (void*)&cE0d, (void*)&cb1e, (void*)&cb1d, (void*)&cwcol0,
    (void*)&h0p, (void*)&h1p,
    (void*)&xh, (void*)&xf, (void*)&y0v,
    (void*)&encWih0, (void*)&decWih0, (void*)&projW, (void*)&projB,
    (void*)&out, (void*)&cntp
  };
  hipLaunchCooperativeKernel((void*)seq2seq_main, dim3(NBLK), dim3(NTHR),
                             kargs, 0, stream);
}

// Round 6
// 23038.498 us; speedup vs baseline: 2.0653x; 1.0373x over previous
//
#include <hip/hip_runtime.h>
#include <stdint.h>

// ---------------------------------------------------------------------------
// Seq2Seq LSTM (2-layer enc + 2-layer autoregressive dec), B=256,H=512,T=288.
// Cooperative persistent kernel; bf16 MFMA 16x16x32 w/ fp32 accum.
// R6 = R4-proven primitives + batch-group decomposition:
//   - 16 independent groups (16 batch rows each) x 16 blocks; group-local
//     R4 barrier (release fetch_add + relaxed RMW poll + acquire) on a
//     private cacheline -> 16 pollers/line instead of 256, no cross-group
//     coupling.
//   - blocks k<8 = layer0 (4 u-tiles each), k>=8 = layer1.
//   - encoder fused to 1 barrier/step (L1_t || L0_{t+1} on disjoint blocks).
//   - c-state in registers; h ping-pong via normal loads/stores published by
//     the barrier's release/acquire (proven R4 path).
// Barriers: 1 + 288 + 2*288 = 865 (R4: 1153).
// ---------------------------------------------------------------------------

typedef __attribute__((ext_vector_type(8))) short bfx8;   // 8 bf16 (4 VGPRs)
typedef __attribute__((ext_vector_type(4))) float fx4;

#define NBLK 256
#define NTHR 256
#define BH   (256*512)

__device__ __forceinline__ unsigned short f2bf(float f){
  unsigned u = __float_as_uint(f);
  u += 0x7FFFu + ((u >> 16) & 1u);          // RNE
  return (unsigned short)(u >> 16);
}
__device__ __forceinline__ float bf2f(unsigned short b){
  return __uint_as_float(((unsigned)b) << 16);
}
__device__ __forceinline__ float sigm(float x){ return 1.0f/(1.0f + __expf(-x)); }
__device__ __forceinline__ float tanhf_(float x){
  x = fminf(12.0f, fmaxf(-12.0f, x));
  float e = __expf(2.0f*x);
  return (e - 1.0f)/(e + 1.0f);
}

// Group barrier (R4-proven primitive, 16 blocks per counter):
// arrival = release RMW (publishes h via wbL2), poll = relaxed RMW (coherent
// RMW-to-RMW), exit = acquire load (invalidate so normal h loads are fresh).
__device__ __forceinline__ void groupbar(unsigned* cnt, unsigned target){
  __syncthreads();
  if (threadIdx.x == 0){
    __hip_atomic_fetch_add(cnt, 1u, __ATOMIC_RELEASE, __HIP_MEMORY_SCOPE_AGENT);
    while (__hip_atomic_fetch_add(cnt, 0u, __ATOMIC_RELAXED,
                                  __HIP_MEMORY_SCOPE_AGENT) < target)
      __builtin_amdgcn_s_sleep(4);
    (void)__hip_atomic_load(cnt, __ATOMIC_ACQUIRE, __HIP_MEMORY_SCOPE_AGENT);
  }
  __syncthreads();
}

// Accumulate K=512: A rows from h (bf16), 4 gate rows of W ([2048][512] bf16).
__device__ __forceinline__ void accK512(fx4* acc, const uint16_t* aq,
                                        const uint16_t* w0, const uint16_t* w1,
                                        const uint16_t* w2, const uint16_t* w3){
  #pragma unroll
  for (int kc = 0; kc < 16; ++kc){
    bfx8 af = *(const bfx8*)(aq + kc*32);
    acc[0] = __builtin_amdgcn_mfma_f32_16x16x32_bf16(af, *(const bfx8*)(w0 + kc*32), acc[0], 0, 0, 0);
    acc[1] = __builtin_amdgcn_mfma_f32_16x16x32_bf16(af, *(const bfx8*)(w1 + kc*32), acc[1], 0, 0, 0);
    acc[2] = __builtin_amdgcn_mfma_f32_16x16x32_bf16(af, *(const bfx8*)(w2 + kc*32), acc[2], 0, 0, 0);
    acc[3] = __builtin_amdgcn_mfma_f32_16x16x32_bf16(af, *(const bfx8*)(w3 + kc*32), acc[3], 0, 0, 0);
  }
}

// LSTM pointwise: c in registers (wave-private), h store to global (normal).
__device__ __forceinline__ void pointwise(fx4* acc, fx4& creg, int bq, int u,
                                          uint16_t* hout){
  #pragma unroll
  for (int r = 0; r < 4; ++r){
    int b = bq + r;
    float iv = sigm(acc[0][r]);
    float fv = sigm(acc[1][r]);
    float gv = tanhf_(acc[2][r]);
    float ov = sigm(acc[3][r]);
    float cn = fv * creg[r] + iv * gv;
    creg[r] = cn;
    hout[b*512 + u] = f2bf(ov * tanhf_(cn));
  }
}

__global__ void __launch_bounds__(NTHR)
seq2seq_main(const uint16_t* __restrict__ Whh0e, const uint16_t* __restrict__ Wih1e,
             const uint16_t* __restrict__ Whh1e, const uint16_t* __restrict__ Whh0d,
             const uint16_t* __restrict__ Wih1d, const uint16_t* __restrict__ Whh1d,
             const uint16_t* __restrict__ Wy,
             const float* __restrict__ E0e, const float* __restrict__ E0d,
             const float* __restrict__ b1e, const float* __restrict__ b1d,
             const float* __restrict__ wcol0,
             uint16_t* h0buf, uint16_t* h1buf,
             const float* __restrict__ xh, const float* __restrict__ xf,
             const float* __restrict__ y0v,
             const float* __restrict__ encWih0, const float* __restrict__ decWih0,
             const float* __restrict__ projW, const float* __restrict__ projB,
             float* out, unsigned* cntBase)
{
  const int tid  = threadIdx.x;
  const int lane = tid & 63;
  const int wvi  = tid >> 6;                 // wave in block, 0..3
  const int g    = blockIdx.x & 15;          // batch group (16 rows)
  const int k    = blockIdx.x >> 4;          // role: 0..7 = L0, 8..15 = L1
  const bool isL0 = (k < 8);
  const int col  = lane & 15;
  const int quad = lane >> 4;
  const int b0 = g << 4;
  const int u0 = (((k & 7) << 2) + wvi) << 4;
  const int u  = u0 + col;
  const int bq = b0 + (quad << 2);
  unsigned* cnt = cntBase + g*32;            // one cacheline per group
  unsigned gen = 0;
  fx4 c0reg = {0.f,0.f,0.f,0.f};
  fx4 c1reg = {0.f,0.f,0.f,0.f};

  uint16_t *h0A = h0buf, *h0B = h0buf + BH;
  uint16_t *h1A = h1buf, *h1B = h1buf + BH;

  auto encCompute = [&](int tt, const uint16_t* h0c, uint16_t* h0n){
    fx4 acc[4];
    #pragma unroll
    for (int gg = 0; gg < 4; ++gg){
      int j = (gg << 9) + u;
      #pragma unroll
      for (int r = 0; r < 4; ++r) acc[gg][r] = E0e[(size_t)(bq + r)*2048 + j];
    }
    accK512(acc, h0c + (b0 + col)*512 + quad*8,
            Whh0e + ((size_t)(0*512 + u))*512 + quad*8,
            Whh0e + ((size_t)(1*512 + u))*512 + quad*8,
            Whh0e + ((size_t)(2*512 + u))*512 + quad*8,
            Whh0e + ((size_t)(3*512 + u))*512 + quad*8);
    float xv[4][8];
    #pragma unroll
    for (int r = 0; r < 4; ++r){
      const float* xr = xh + ((size_t)(bq + r)*288 + tt)*8;
      #pragma unroll
      for (int kk = 0; kk < 8; ++kk) xv[r][kk] = xr[kk];
    }
    #pragma unroll
    for (int gg = 0; gg < 4; ++gg){
      const float* wr = encWih0 + (size_t)((gg << 9) + u)*24;
      #pragma unroll
      for (int kk = 0; kk < 8; ++kk){
        float w = wr[kk];
        #pragma unroll
        for (int r = 0; r < 4; ++r) acc[gg][r] += w * xv[r][kk];
      }
    }
    pointwise(acc, c0reg, bq, u, h0n);
  };

  auto decCompute = [&](int tt, const uint16_t* h0c, const uint16_t* h1c,
                        uint16_t* h0n){
    fx4 acc[4];
    #pragma unroll
    for (int gg = 0; gg < 4; ++gg){
      int j = (gg << 9) + u;
      #pragma unroll
      for (int r = 0; r < 4; ++r) acc[gg][r] = E0d[(size_t)(bq + r)*2048 + j];
    }
    accK512(acc, h0c + (b0 + col)*512 + quad*8,
            Whh0d + ((size_t)(0*512 + u))*512 + quad*8,
            Whh0d + ((size_t)(1*512 + u))*512 + quad*8,
            Whh0d + ((size_t)(2*512 + u))*512 + quad*8,
            Whh0d + ((size_t)(3*512 + u))*512 + quad*8);
    if (tt > 0)
      accK512(acc, h1c + (b0 + col)*512 + quad*8,
              Wy + ((size_t)(0*512 + u))*512 + quad*8,
              Wy + ((size_t)(1*512 + u))*512 + quad*8,
              Wy + ((size_t)(2*512 + u))*512 + quad*8,
              Wy + ((size_t)(3*512 + u))*512 + quad*8);
    float s[4];
    #pragma unroll
    for (int r = 0; r < 4; ++r) s[r] = (tt == 0) ? y0v[bq + r] : projB[0];
    #pragma unroll
    for (int gg = 0; gg < 4; ++gg){
      float w = wcol0[(gg << 9) + u];
      #pragma unroll
      for (int r = 0; r < 4; ++r) acc[gg][r] += w * s[r];
    }
    float xv[4][6];
    #pragma unroll
    for (int r = 0; r < 4; ++r){
      const float* xr = xf + ((size_t)(bq + r)*288 + tt)*6;
      #pragma unroll
      for (int kk = 0; kk < 6; ++kk) xv[r][kk] = xr[kk];
    }
    #pragma unroll
    for (int gg = 0; gg < 4; ++gg){
      const float* wr = decWih0 + (size_t)((gg << 9) + u)*23 + 1;
      #pragma unroll
      for (int kk = 0; kk < 6; ++kk){
        float w = wr[kk];
        #pragma unroll
        for (int r = 0; r < 4; ++r) acc[gg][r] += w * xv[r][kk];
      }
    }
    pointwise(acc, c0reg, bq, u, h0n);
  };

  auto l1Compute = [&](const uint16_t* Whh1, const uint16_t* Wih1,
                       const float* b1, const uint16_t* h1c,
                       const uint16_t* h0n, uint16_t* h1n){
    fx4 acc[4];
    #pragma unroll
    for (int gg = 0; gg < 4; ++gg){
      float bb = b1[(gg << 9) + u];
      #pragma unroll
      for (int r = 0; r < 4; ++r) acc[gg][r] = bb;
    }
    accK512(acc, h1c + (b0 + col)*512 + quad*8,
            Whh1 + ((size_t)(0*512 + u))*512 + quad*8,
            Whh1 + ((size_t)(1*512 + u))*512 + quad*8,
            Whh1 + ((size_t)(2*512 + u))*512 + quad*8,
            Whh1 + ((size_t)(3*512 + u))*512 + quad*8);
    accK512(acc, h0n + (b0 + col)*512 + quad*8,
            Wih1 + ((size_t)(0*512 + u))*512 + quad*8,
            Wih1 + ((size_t)(1*512 + u))*512 + quad*8,
            Wih1 + ((size_t)(2*512 + u))*512 + quad*8,
            Wih1 + ((size_t)(3*512 + u))*512 + quad*8);
    pointwise(acc, c1reg, bq, u, h1n);
  };

  // emitY: block k==8, wave wvi handles rows b0+wvi*4..+3 (64-lane dot each)
  auto emitY = [&](const uint16_t* h1cur, int tt){
    #pragma unroll 1
    for (int j = 0; j < 4; ++j){
      int b = b0 + (wvi << 2) + j;
      const uint16_t* hr = h1cur + b*512 + lane*8;
      const float* pw = projW + lane*8;
      float part = 0.f;
      #pragma unroll
      for (int kk = 0; kk < 8; ++kk) part += bf2f(hr[kk]) * pw[kk];
      #pragma unroll
      for (int off = 32; off > 0; off >>= 1) part += __shfl_down(part, off);
      if (lane == 0) out[(size_t)b*288 + tt] = part + projB[0];
    }
  };

  // ---- prologue: enc L0 t=0 (h_{-1}=0 via memset) ----
  if (isL0) encCompute(0, h0A, h0B);
  groupbar(cnt, (++gen)*16);
  { uint16_t* t_ = h0A; h0A = h0B; h0B = t_; }   // h0A = h0_0

  // ---- encoder: 1 barrier/step; L1_t (k>=8) || L0_{t+1} (k<8) ----
  #pragma unroll 1
  for (int t = 0; t < 288; ++t){
    if (isL0){
      if (t < 287) encCompute(t + 1, h0A, h0B);
    } else {
      l1Compute(Whh1e, Wih1e, b1e, h1A, h0A, h1B);
    }
    groupbar(cnt, (++gen)*16);
    { uint16_t* t_ = h1A; h1A = h1B; h1B = t_; }
    if (t < 287){ uint16_t* t_ = h0A; h0A = h0B; h0B = t_; }
  }
  // h0A = h0_287, h1A = h1_287; c continues into decoder.

  // ---- decoder: 2 barriers/step ----
  #pragma unroll 1
  for (int t = 0; t < 288; ++t){
    if (isL0){
      decCompute(t, h0A, h1A, h0B);
    } else if (k == 8 && t > 0){
      emitY(h1A, t - 1);
    }
    groupbar(cnt, (++gen)*16);
    if (!isL0){
      l1Compute(Whh1d, Wih1d, b1d, h1A, h0B, h1B);
    }
    groupbar(cnt, (++gen)*16);
    { uint16_t* t_ = h0A; h0A = h0B; h0B = t_; }
    { uint16_t* t_ = h1A; h1A = h1B; h1B = t_; }
  }

  // final y_287
  if (k == 8) emitY(h1A, 287);
}

// ---------------- prep: bf16 weights, Wy fold, emb+bias fold ----------------
#define PREP_S 1048576
#define PREP_TOTAL (8*PREP_S + 6144)

__global__ void __launch_bounds__(256)
prep_kernel(const float* __restrict__ encWih0, const float* __restrict__ encWhh0,
            const float* __restrict__ encWih1, const float* __restrict__ encWhh1,
            const float* __restrict__ decWih0, const float* __restrict__ decWhh0,
            const float* __restrict__ decWih1, const float* __restrict__ decWhh1,
            const float* __restrict__ encbih0, const float* __restrict__ encbhh0,
            const float* __restrict__ encbih1, const float* __restrict__ encbhh1,
            const float* __restrict__ decbih0, const float* __restrict__ decbhh0,
            const float* __restrict__ decbih1, const float* __restrict__ decbhh1,
            const float* __restrict__ projW, const float* __restrict__ emb,
            const int* __restrict__ turb,
            uint16_t* Whh0e, uint16_t* Wih1e, uint16_t* Whh1e,
            uint16_t* Whh0d, uint16_t* Wih1d, uint16_t* Whh1d, uint16_t* Wy,
            float* E0e, float* E0d, float* b1e, float* b1d, float* wcol0)
{
  int i = blockIdx.x*256 + threadIdx.x;
  if (i >= PREP_TOTAL) return;
  if (i < 6*PREP_S){
    int w = i >> 20, r = i & (PREP_S - 1);
    const float* src = (w==0)?encWhh0:(w==1)?encWih1:(w==2)?encWhh1:
                       (w==3)?decWhh0:(w==4)?decWih1:decWhh1;
    uint16_t* dst = (w==0)?Whh0e:(w==1)?Wih1e:(w==2)?Whh1e:
                    (w==3)?Whh0d:(w==4)?Wih1d:Whh1d;
    dst[r] = f2bf(src[r]);
  } else if (i < 7*PREP_S){
    int r = i - 6*PREP_S; int j = r >> 9, kk = r & 511;
    Wy[r] = f2bf(decWih0[(size_t)j*23] * projW[kk]);
  } else if (i < 7*PREP_S + 524288){
    int r = i - 7*PREP_S; int b = r >> 11, j = r & 2047;
    float s = encbih0[j] + encbhh0[j];
    const float* e = emb + (size_t)turb[b]*16;
    const float* wr = encWih0 + (size_t)j*24 + 8;
    #pragma unroll
    for (int m = 0; m < 16; ++m) s += e[m]*wr[m];
    E0e[r] = s;
  } else if (i < 8*PREP_S){
    int r = i - 7*PREP_S - 524288; int b = r >> 11, j = r & 2047;
    float s = decbih0[j] + decbhh0[j];
    const float* e = emb + (size_t)turb[b]*16;
    const float* wr = decWih0 + (size_t)j*23 + 7;
    #pragma unroll
    for (int m = 0; m < 16; ++m) s += e[m]*wr[m];
    E0d[r] = s;
  } else {
    int r = i - 8*PREP_S;
    if (r < 2048)      b1e[r] = encbih1[r] + encbhh1[r];
    else if (r < 4096){ int j = r - 2048; b1d[j] = decbih1[j] + decbhh1[j]; }
    else              { int j = r - 4096; wcol0[j] = decWih0[(size_t)j*23]; }
  }
}

// ---------------------------------------------------------------------------
extern "C" void kernel_launch(void* const* d_in, const int* in_sizes, int n_in,
                              void* d_out, int out_size, void* d_ws, size_t ws_size,
                              hipStream_t stream)
{
  const float* xh      = (const float*)d_in[0];
  const float* xf      = (const float*)d_in[1];
  const float* y0v     = (const float*)d_in[2];
  const int*   turb    = (const int*)d_in[3];
  const float* emb     = (const float*)d_in[5];
  const float* encWih0 = (const float*)d_in[6];
  const float* encWhh0 = (const float*)d_in[7];
  const float* encbih0 = (const float*)d_in[8];
  const float* encbhh0 = (const float*)d_in[9];
  const float* encWih1 = (const float*)d_in[10];
  const float* encWhh1 = (const float*)d_in[11];
  const float* encbih1 = (const float*)d_in[12];
  const float* encbhh1 = (const float*)d_in[13];
  const float* decWih0 = (const float*)d_in[14];
  const float* decWhh0 = (const float*)d_in[15];
  const float* decbih0 = (const float*)d_in[16];
  const float* decbhh0 = (const float*)d_in[17];
  const float* decWih1 = (const float*)d_in[18];
  const float* decWhh1 = (const float*)d_in[19];
  const float* decbih1 = (const float*)d_in[20];
  const float* decbhh1 = (const float*)d_in[21];
  const float* projW   = (const float*)d_in[22];
  const float* projB   = (const float*)d_in[23];
  float* out = (float*)d_out;

  char* ws = (char*)d_ws;
  constexpr size_t SZW = (size_t)2048*512*2;
  constexpr size_t OFF_Whh0e = 0;
  constexpr size_t OFF_Wih1e = SZW;
  constexpr size_t OFF_Whh1e = 2*SZW;
  constexpr size_t OFF_Whh0d = 3*SZW;
  constexpr size_t OFF_Wih1d = 4*SZW;
  constexpr size_t OFF_Whh1d = 5*SZW;
  constexpr size_t OFF_Wy    = 6*SZW;
  constexpr size_t OFF_E0e   = 7*SZW;
  constexpr size_t OFF_E0d   = OFF_E0e + 2097152;
  constexpr size_t OFF_b1e   = OFF_E0d + 2097152;
  constexpr size_t OFF_b1d   = OFF_b1e + 8192;
  constexpr size_t OFF_wcol0 = OFF_b1d + 8192;
  constexpr size_t OFF_h0    = OFF_wcol0 + 8192;
  constexpr size_t OFF_h1    = OFF_h0 + 524288;
  constexpr size_t OFF_cnt   = OFF_h1 + 524288;
  constexpr size_t ZERO_BYTES = 2*524288 + 2048;  // h0,h1 ping-pong + 16 counters

  uint16_t* Whh0e = (uint16_t*)(ws + OFF_Whh0e);
  uint16_t* Wih1e = (uint16_t*)(ws + OFF_Wih1e);
  uint16_t* Whh1e = (uint16_t*)(ws + OFF_Whh1e);
  uint16_t* Whh0d = (uint16_t*)(ws + OFF_Whh0d);
  uint16_t* Wih1d = (uint16_t*)(ws + OFF_Wih1d);
  uint16_t* Whh1d = (uint16_t*)(ws + OFF_Whh1d);
  uint16_t* Wyp   = (uint16_t*)(ws + OFF_Wy);
  float* E0e   = (float*)(ws + OFF_E0e);
  float* E0d   = (float*)(ws + OFF_E0d);
  float* b1e   = (float*)(ws + OFF_b1e);
  float* b1d   = (float*)(ws + OFF_b1d);
  float* wcol0 = (float*)(ws + OFF_wcol0);
  uint16_t* h0p = (uint16_t*)(ws + OFF_h0);
  uint16_t* h1p = (uint16_t*)(ws + OFF_h1);
  unsigned* cntp = (unsigned*)(ws + OFF_cnt);

  hipMemsetAsync(ws + OFF_h0, 0, ZERO_BYTES, stream);

  prep_kernel<<<dim3((PREP_TOTAL + 255)/256), dim3(256), 0, stream>>>(
      encWih0, encWhh0, encWih1, encWhh1, decWih0, decWhh0, decWih1, decWhh1,
      encbih0, encbhh0, encbih1, encbhh1, decbih0, decbhh0, decbih1, decbhh1,
      projW, emb, turb,
      Whh0e, Wih1e, Whh1e, Whh0d, Wih1d, Whh1d, Wyp,
      E0e, E0d, b1e, b1d, wcol0);

  const uint16_t* cWhh0e = Whh0e; const uint16_t* cWih1e = Wih1e;
  const uint16_t* cWhh1e = Whh1e; const uint16_t* cWhh0d = Whh0d;
  const uint16_t* cWih1d = Wih1d; const uint16_t* cWhh1d = Whh1d;
  const uint16_t* cWy = Wyp;
  const float* cE0e = E0e; const float* cE0d = E0d;
  const float* cb1e = b1e; const float* cb1d = b1d; const float* cwcol0 = wcol0;

  void* kargs[] = {
    (void*)&cWhh0e, (void*)&cWih1e, (void*)&cWhh1e, (void*)&cWhh0d,
    (void*)&cWih1d, (void*)&cWhh1d, (void*)&cWy,
    (void*)&cE0e, (void*)&cE0d, (void*)&cb1e, (void*)&cb1d, (void*)&cwcol0,
    (void*)&h0p, (void*)&h1p,
    (void*)&xh, (void*)&xf, (void*)&y0v,
    (void*)&encWih0, (void*)&decWih0, (void*)&projW, (void*)&projB,
    (void*)&out, (void*)&cntp
  };
  hipLaunchCooperativeKernel((void*)seq2seq_main, dim3(NBLK), dim3(NTHR),
                             kargs, 0, stream);
}

// Round 7
// 22132.286 us; speedup vs baseline: 2.1499x; 1.0409x over previous
//
#include <hip/hip_runtime.h>
#include <stdint.h>

// ---------------------------------------------------------------------------
// Seq2Seq LSTM (2-layer enc + 2-layer autoregressive dec), B=256,H=512,T=288.
// Cooperative persistent kernel; bf16 MFMA 16x16x32 w/ fp32 accum.
// R7 = R6 with the group/role index mapping transposed:
//   g = blk>>4, k = blk&15  ->  group g's blocks = {16g+k} -> XCD = k%8.
//   Each XCD now hosts only k in {x, x+8}: ONE L0 u-slice + ONE L1 u-slice
//   (~0.75MB) instead of the full weight set (~14MB) -> the per-barrier
//   acquire-invalidate refetch collapses 21MB -> <1MB per barrier.
//   Per-group counters retained (16 pollers/cacheline, no global RMW storm).
// Everything else identical to the PASSING R6 (rel/acq barrier, plain h
// loads/stores, c in registers, enc fused 1 barrier/step).
// ---------------------------------------------------------------------------

typedef __attribute__((ext_vector_type(8))) short bfx8;   // 8 bf16 (4 VGPRs)
typedef __attribute__((ext_vector_type(4))) float fx4;

#define NBLK 256
#define NTHR 256
#define BH   (256*512)

__device__ __forceinline__ unsigned short f2bf(float f){
  unsigned u = __float_as_uint(f);
  u += 0x7FFFu + ((u >> 16) & 1u);          // RNE
  return (unsigned short)(u >> 16);
}
__device__ __forceinline__ float bf2f(unsigned short b){
  return __uint_as_float(((unsigned)b) << 16);
}
__device__ __forceinline__ float sigm(float x){ return 1.0f/(1.0f + __expf(-x)); }
__device__ __forceinline__ float tanhf_(float x){
  x = fminf(12.0f, fmaxf(-12.0f, x));
  float e = __expf(2.0f*x);
  return (e - 1.0f)/(e + 1.0f);
}

// Group barrier (R4/R6-proven primitive, 16 blocks per counter):
// arrival = release RMW (publishes h via wbL2), poll = relaxed RMW (coherent
// RMW-to-RMW), exit = acquire load (invalidate so normal h loads are fresh).
__device__ __forceinline__ void groupbar(unsigned* cnt, unsigned target){
  __syncthreads();
  if (threadIdx.x == 0){
    __hip_atomic_fetch_add(cnt, 1u, __ATOMIC_RELEASE, __HIP_MEMORY_SCOPE_AGENT);
    while (__hip_atomic_fetch_add(cnt, 0u, __ATOMIC_RELAXED,
                                  __HIP_MEMORY_SCOPE_AGENT) < target)
      __builtin_amdgcn_s_sleep(4);
    (void)__hip_atomic_load(cnt, __ATOMIC_ACQUIRE, __HIP_MEMORY_SCOPE_AGENT);
  }
  __syncthreads();
}

// Accumulate K=512: A rows from h (bf16), 4 gate rows of W ([2048][512] bf16).
__device__ __forceinline__ void accK512(fx4* acc, const uint16_t* aq,
                                        const uint16_t* w0, const uint16_t* w1,
                                        const uint16_t* w2, const uint16_t* w3){
  #pragma unroll
  for (int kc = 0; kc < 16; ++kc){
    bfx8 af = *(const bfx8*)(aq + kc*32);
    acc[0] = __builtin_amdgcn_mfma_f32_16x16x32_bf16(af, *(const bfx8*)(w0 + kc*32), acc[0], 0, 0, 0);
    acc[1] = __builtin_amdgcn_mfma_f32_16x16x32_bf16(af, *(const bfx8*)(w1 + kc*32), acc[1], 0, 0, 0);
    acc[2] = __builtin_amdgcn_mfma_f32_16x16x32_bf16(af, *(const bfx8*)(w2 + kc*32), acc[2], 0, 0, 0);
    acc[3] = __builtin_amdgcn_mfma_f32_16x16x32_bf16(af, *(const bfx8*)(w3 + kc*32), acc[3], 0, 0, 0);
  }
}

// LSTM pointwise: c in registers (wave-private), h store to global (normal).
__device__ __forceinline__ void pointwise(fx4* acc, fx4& creg, int bq, int u,
                                          uint16_t* hout){
  #pragma unroll
  for (int r = 0; r < 4; ++r){
    int b = bq + r;
    float iv = sigm(acc[0][r]);
    float fv = sigm(acc[1][r]);
    float gv = tanhf_(acc[2][r]);
    float ov = sigm(acc[3][r]);
    float cn = fv * creg[r] + iv * gv;
    creg[r] = cn;
    hout[b*512 + u] = f2bf(ov * tanhf_(cn));
  }
}

__global__ void __launch_bounds__(NTHR)
seq2seq_main(const uint16_t* __restrict__ Whh0e, const uint16_t* __restrict__ Wih1e,
             const uint16_t* __restrict__ Whh1e, const uint16_t* __restrict__ Whh0d,
             const uint16_t* __restrict__ Wih1d, const uint16_t* __restrict__ Whh1d,
             const uint16_t* __restrict__ Wy,
             const float* __restrict__ E0e, const float* __restrict__ E0d,
             const float* __restrict__ b1e, const float* __restrict__ b1d,
             const float* __restrict__ wcol0,
             uint16_t* h0buf, uint16_t* h1buf,
             const float* __restrict__ xh, const float* __restrict__ xf,
             const float* __restrict__ y0v,
             const float* __restrict__ encWih0, const float* __restrict__ decWih0,
             const float* __restrict__ projW, const float* __restrict__ projB,
             float* out, unsigned* cntBase)
{
  const int tid  = threadIdx.x;
  const int lane = tid & 63;
  const int wvi  = tid >> 6;                 // wave in block, 0..3
  const int g    = blockIdx.x >> 4;          // batch group (16 rows)  [R7 swap]
  const int k    = blockIdx.x & 15;          // role: 0..7 = L0, 8..15 = L1
  const bool isL0 = (k < 8);
  const int col  = lane & 15;
  const int quad = lane >> 4;
  const int b0 = g << 4;
  const int u0 = (((k & 7) << 2) + wvi) << 4;
  const int u  = u0 + col;
  const int bq = b0 + (quad << 2);
  unsigned* cnt = cntBase + g*32;            // one cacheline per group
  unsigned gen = 0;
  fx4 c0reg = {0.f,0.f,0.f,0.f};
  fx4 c1reg = {0.f,0.f,0.f,0.f};

  uint16_t *h0A = h0buf, *h0B = h0buf + BH;
  uint16_t *h1A = h1buf, *h1B = h1buf + BH;

  auto encCompute = [&](int tt, const uint16_t* h0c, uint16_t* h0n){
    fx4 acc[4];
    #pragma unroll
    for (int gg = 0; gg < 4; ++gg){
      int j = (gg << 9) + u;
      #pragma unroll
      for (int r = 0; r < 4; ++r) acc[gg][r] = E0e[(size_t)(bq + r)*2048 + j];
    }
    accK512(acc, h0c + (b0 + col)*512 + quad*8,
            Whh0e + ((size_t)(0*512 + u))*512 + quad*8,
            Whh0e + ((size_t)(1*512 + u))*512 + quad*8,
            Whh0e + ((size_t)(2*512 + u))*512 + quad*8,
            Whh0e + ((size_t)(3*512 + u))*512 + quad*8);
    float xv[4][8];
    #pragma unroll
    for (int r = 0; r < 4; ++r){
      const float* xr = xh + ((size_t)(bq + r)*288 + tt)*8;
      #pragma unroll
      for (int kk = 0; kk < 8; ++kk) xv[r][kk] = xr[kk];
    }
    #pragma unroll
    for (int gg = 0; gg < 4; ++gg){
      const float* wr = encWih0 + (size_t)((gg << 9) + u)*24;
      #pragma unroll
      for (int kk = 0; kk < 8; ++kk){
        float w = wr[kk];
        #pragma unroll
        for (int r = 0; r < 4; ++r) acc[gg][r] += w * xv[r][kk];
      }
    }
    pointwise(acc, c0reg, bq, u, h0n);
  };

  auto decCompute = [&](int tt, const uint16_t* h0c, const uint16_t* h1c,
                        uint16_t* h0n){
    fx4 acc[4];
    #pragma unroll
    for (int gg = 0; gg < 4; ++gg){
      int j = (gg << 9) + u;
      #pragma unroll
      for (int r = 0; r < 4; ++r) acc[gg][r] = E0d[(size_t)(bq + r)*2048 + j];
    }
    accK512(acc, h0c + (b0 + col)*512 + quad*8,
            Whh0d + ((size_t)(0*512 + u))*512 + quad*8,
            Whh0d + ((size_t)(1*512 + u))*512 + quad*8,
            Whh0d + ((size_t)(2*512 + u))*512 + quad*8,
            Whh0d + ((size_t)(3*512 + u))*512 + quad*8);
    if (tt > 0)
      accK512(acc, h1c + (b0 + col)*512 + quad*8,
              Wy + ((size_t)(0*512 + u))*512 + quad*8,
              Wy + ((size_t)(1*512 + u))*512 + quad*8,
              Wy + ((size_t)(2*512 + u))*512 + quad*8,
              Wy + ((size_t)(3*512 + u))*512 + quad*8);
    float s[4];
    #pragma unroll
    for (int r = 0; r < 4; ++r) s[r] = (tt == 0) ? y0v[bq + r] : projB[0];
    #pragma unroll
    for (int gg = 0; gg < 4; ++gg){
      float w = wcol0[(gg << 9) + u];
      #pragma unroll
      for (int r = 0; r < 4; ++r) acc[gg][r] += w * s[r];
    }
    float xv[4][6];
    #pragma unroll
    for (int r = 0; r < 4; ++r){
      const float* xr = xf + ((size_t)(bq + r)*288 + tt)*6;
      #pragma unroll
      for (int kk = 0; kk < 6; ++kk) xv[r][kk] = xr[kk];
    }
    #pragma unroll
    for (int gg = 0; gg < 4; ++gg){
      const float* wr = decWih0 + (size_t)((gg << 9) + u)*23 + 1;
      #pragma unroll
      for (int kk = 0; kk < 6; ++kk){
        float w = wr[kk];
        #pragma unroll
        for (int r = 0; r < 4; ++r) acc[gg][r] += w * xv[r][kk];
      }
    }
    pointwise(acc, c0reg, bq, u, h0n);
  };

  auto l1Compute = [&](const uint16_t* Whh1, const uint16_t* Wih1,
                       const float* b1, const uint16_t* h1c,
                       const uint16_t* h0n, uint16_t* h1n){
    fx4 acc[4];
    #pragma unroll
    for (int gg = 0; gg < 4; ++gg){
      float bb = b1[(gg << 9) + u];
      #pragma unroll
      for (int r = 0; r < 4; ++r) acc[gg][r] = bb;
    }
    accK512(acc, h1c + (b0 + col)*512 + quad*8,
            Whh1 + ((size_t)(0*512 + u))*512 + quad*8,
            Whh1 + ((size_t)(1*512 + u))*512 + quad*8,
            Whh1 + ((size_t)(2*512 + u))*512 + quad*8,
            Whh1 + ((size_t)(3*512 + u))*512 + quad*8);
    accK512(acc, h0n + (b0 + col)*512 + quad*8,
            Wih1 + ((size_t)(0*512 + u))*512 + quad*8,
            Wih1 + ((size_t)(1*512 + u))*512 + quad*8,
            Wih1 + ((size_t)(2*512 + u))*512 + quad*8,
            Wih1 + ((size_t)(3*512 + u))*512 + quad*8);
    pointwise(acc, c1reg, bq, u, h1n);
  };

  // emitY: block k==8, wave wvi handles rows b0+wvi*4..+3 (64-lane dot each)
  auto emitY = [&](const uint16_t* h1cur, int tt){
    #pragma unroll 1
    for (int j = 0; j < 4; ++j){
      int b = b0 + (wvi << 2) + j;
      const uint16_t* hr = h1cur + b*512 + lane*8;
      const float* pw = projW + lane*8;
      float part = 0.f;
      #pragma unroll
      for (int kk = 0; kk < 8; ++kk) part += bf2f(hr[kk]) * pw[kk];
      #pragma unroll
      for (int off = 32; off > 0; off >>= 1) part += __shfl_down(part, off);
      if (lane == 0) out[(size_t)b*288 + tt] = part + projB[0];
    }
  };

  // ---- prologue: enc L0 t=0 (h_{-1}=0 via memset) ----
  if (isL0) encCompute(0, h0A, h0B);
  groupbar(cnt, (++gen)*16);
  { uint16_t* t_ = h0A; h0A = h0B; h0B = t_; }   // h0A = h0_0

  // ---- encoder: 1 barrier/step; L1_t (k>=8) || L0_{t+1} (k<8) ----
  #pragma unroll 1
  for (int t = 0; t < 288; ++t){
    if (isL0){
      if (t < 287) encCompute(t + 1, h0A, h0B);
    } else {
      l1Compute(Whh1e, Wih1e, b1e, h1A, h0A, h1B);
    }
    groupbar(cnt, (++gen)*16);
    { uint16_t* t_ = h1A; h1A = h1B; h1B = t_; }
    if (t < 287){ uint16_t* t_ = h0A; h0A = h0B; h0B = t_; }
  }
  // h0A = h0_287, h1A = h1_287; c continues into decoder.

  // ---- decoder: 2 barriers/step ----
  #pragma unroll 1
  for (int t = 0; t < 288; ++t){
    if (isL0){
      decCompute(t, h0A, h1A, h0B);
    } else if (k == 8 && t > 0){
      emitY(h1A, t - 1);
    }
    groupbar(cnt, (++gen)*16);
    if (!isL0){
      l1Compute(Whh1d, Wih1d, b1d, h1A, h0B, h1B);
    }
    groupbar(cnt, (++gen)*16);
    { uint16_t* t_ = h0A; h0A = h0B; h0B = t_; }
    { uint16_t* t_ = h1A; h1A = h1B; h1B = t_; }
  }

  // final y_287
  if (k == 8) emitY(h1A, 287);
}

// ---------------- prep: bf16 weights, Wy fold, emb+bias fold ----------------
#define PREP_S 1048576
#define PREP_TOTAL (8*PREP_S + 6144)

__global__ void __launch_bounds__(256)
prep_kernel(const float* __restrict__ encWih0, const float* __restrict__ encWhh0,
            const float* __restrict__ encWih1, const float* __restrict__ encWhh1,
            const float* __restrict__ decWih0, const float* __restrict__ decWhh0,
            const float* __restrict__ decWih1, const float* __restrict__ decWhh1,
            const float* __restrict__ encbih0, const float* __restrict__ encbhh0,
            const float* __restrict__ encbih1, const float* __restrict__ encbhh1,
            const float* __restrict__ decbih0, const float* __restrict__ decbhh0,
            const float* __restrict__ decbih1, const float* __restrict__ decbhh1,
            const float* __restrict__ projW, const float* __restrict__ emb,
            const int* __restrict__ turb,
            uint16_t* Whh0e, uint16_t* Wih1e, uint16_t* Whh1e,
            uint16_t* Whh0d, uint16_t* Wih1d, uint16_t* Whh1d, uint16_t* Wy,
            float* E0e, float* E0d, float* b1e, float* b1d, float* wcol0)
{
  int i = blockIdx.x*256 + threadIdx.x;
  if (i >= PREP_TOTAL) return;
  if (i < 6*PREP_S){
    int w = i >> 20, r = i & (PREP_S - 1);
    const float* src = (w==0)?encWhh0:(w==1)?encWih1:(w==2)?encWhh1:
                       (w==3)?decWhh0:(w==4)?decWih1:decWhh1;
    uint16_t* dst = (w==0)?Whh0e:(w==1)?Wih1e:(w==2)?Whh1e:
                    (w==3)?Whh0d:(w==4)?Wih1d:Whh1d;
    dst[r] = f2bf(src[r]);
  } else if (i < 7*PREP_S){
    int r = i - 6*PREP_S; int j = r >> 9, kk = r & 511;
    Wy[r] = f2bf(decWih0[(size_t)j*23] * projW[kk]);
  } else if (i < 7*PREP_S + 524288){
    int r = i - 7*PREP_S; int b = r >> 11, j = r & 2047;
    float s = encbih0[j] + encbhh0[j];
    const float* e = emb + (size_t)turb[b]*16;
    const float* wr = encWih0 + (size_t)j*24 + 8;
    #pragma unroll
    for (int m = 0; m < 16; ++m) s += e[m]*wr[m];
    E0e[r] = s;
  } else if (i < 8*PREP_S){
    int r = i - 7*PREP_S - 524288; int b = r >> 11, j = r & 2047;
    float s = decbih0[j] + decbhh0[j];
    const float* e = emb + (size_t)turb[b]*16;
    const float* wr = decWih0 + (size_t)j*23 + 7;
    #pragma unroll
    for (int m = 0; m < 16; ++m) s += e[m]*wr[m];
    E0d[r] = s;
  } else {
    int r = i - 8*PREP_S;
    if (r < 2048)      b1e[r] = encbih1[r] + encbhh1[r];
    else if (r < 4096){ int j = r - 2048; b1d[j] = decbih1[j] + decbhh1[j]; }
    else              { int j = r - 4096; wcol0[j] = decWih0[(size_t)j*23]; }
  }
}

// ---------------------------------------------------------------------------
extern "C" void kernel_launch(void* const* d_in, const int* in_sizes, int n_in,
                              void* d_out, int out_size, void* d_ws, size_t ws_size,
                              hipStream_t stream)
{
  const float* xh      = (const float*)d_in[0];
  const float* xf      = (const float*)d_in[1];
  const float* y0v     = (const float*)d_in[2];
  const int*   turb    = (const int*)d_in[3];
  const float* emb     = (const float*)d_in[5];
  const float* encWih0 = (const float*)d_in[6];
  const float* encWhh0 = (const float*)d_in[7];
  const float* encbih0 = (const float*)d_in[8];
  const float* encbhh0 = (const float*)d_in[9];
  const float* encWih1 = (const float*)d_in[10];
  const float* encWhh1 = (const float*)d_in[11];
  const float* encbih1 = (const float*)d_in[12];
  const float* encbhh1 = (const float*)d_in[13];
  const float* decWih0 = (const float*)d_in[14];
  const float* decWhh0 = (const float*)d_in[15];
  const float* decbih0 = (const float*)d_in[16];
  const float* decbhh0 = (const float*)d_in[17];
  const float* decWih1 = (const float*)d_in[18];
  const float* decWhh1 = (const float*)d_in[19];
  const float* decbih1 = (const float*)d_in[20];
  const float* decbhh1 = (const float*)d_in[21];
  const float* projW   = (const float*)d_in[22];
  const float* projB   = (const float*)d_in[23];
  float* out = (float*)d_out;

  char* ws = (char*)d_ws;
  constexpr size_t SZW = (size_t)2048*512*2;
  constexpr size_t OFF_Whh0e = 0;
  constexpr size_t OFF_Wih1e = SZW;
  constexpr size_t OFF_Whh1e = 2*SZW;
  constexpr size_t OFF_Whh0d = 3*SZW;
  constexpr size_t OFF_Wih1d = 4*SZW;
  constexpr size_t OFF_Whh1d = 5*SZW;
  constexpr size_t OFF_Wy    = 6*SZW;
  constexpr size_t OFF_E0e   = 7*SZW;
  constexpr size_t OFF_E0d   = OFF_E0e + 2097152;
  constexpr size_t OFF_b1e   = OFF_E0d + 2097152;
  constexpr size_t OFF_b1d   = OFF_b1e + 8192;
  constexpr size_t OFF_wcol0 = OFF_b1d + 8192;
  constexpr size_t OFF_h0    = OFF_wcol0 + 8192;
  constexpr size_t OFF_h1    = OFF_h0 + 524288;
  constexpr size_t OFF_cnt   = OFF_h1 + 524288;
  constexpr size_t ZERO_BYTES = 2*524288 + 2048;  // h0,h1 ping-pong + 16 counters

  uint16_t* Whh0e = (uint16_t*)(ws + OFF_Whh0e);
  uint16_t* Wih1e = (uint16_t*)(ws + OFF_Wih1e);
  uint16_t* Whh1e = (uint16_t*)(ws + OFF_Whh1e);
  uint16_t* Whh0d = (uint16_t*)(ws + OFF_Whh0d);
  uint16_t* Wih1d = (uint16_t*)(ws + OFF_Wih1d);
  uint16_t* Whh1d = (uint16_t*)(ws + OFF_Whh1d);
  uint16_t* Wyp   = (uint16_t*)(ws + OFF_Wy);
  float* E0e   = (float*)(ws + OFF_E0e);
  float* E0d   = (float*)(ws + OFF_E0d);
  float* b1e   = (float*)(ws + OFF_b1e);
  float* b1d   = (float*)(ws + OFF_b1d);
  float* wcol0 = (float*)(ws + OFF_wcol0);
  uint16_t* h0p = (uint16_t*)(ws + OFF_h0);
  uint16_t* h1p = (uint16_t*)(ws + OFF_h1);
  unsigned* cntp = (unsigned*)(ws + OFF_cnt);

  hipMemsetAsync(ws + OFF_h0, 0, ZERO_BYTES, stream);

  prep_kernel<<<dim3((PREP_TOTAL + 255)/256), dim3(256), 0, stream>>>(
      encWih0, encWhh0, encWih1, encWhh1, decWih0, decWhh0, decWih1, decWhh1,
      encbih0, encbhh0, encbih1, encbhh1, decbih0, decbhh0, decbih1, decbhh1,
      projW, emb, turb,
      Whh0e, Wih1e, Whh1e, Whh0d, Wih1d, Whh1d, Wyp,
      E0e, E0d, b1e, b1d, wcol0);

  const uint16_t* cWhh0e = Whh0e; const uint16_t* cWih1e = Wih1e;
  const uint16_t* cWhh1e = Whh1e; const uint16_t* cWhh0d = Whh0d;
  const uint16_t* cWih1d = Wih1d; const uint16_t* cWhh1d = Whh1d;
  const uint16_t* cWy = Wyp;
  const float* cE0e = E0e; const float* cE0d = E0d;
  const float* cb1e = b1e; const float* cb1d = b1d; const float* cwcol0 = wcol0;

  void* kargs[] = {
    (void*)&cWhh0e, (void*)&cWih1e, (void*)&cWhh1e, (void*)&cWhh0d,
    (void*)&cWih1d, (void*)&cWhh1d, (void*)&cWy,
    (void*)&cE0e, (void*)&cE0d, (void*)&cb1e, (void*)&cb1d, (void*)&cwcol0,
    (void*)&h0p, (void*)&h1p,
    (void*)&xh, (void*)&xf, (void*)&y0v,
    (void*)&encWih0, (void*)&decWih0, (void*)&projW, (void*)&projB,
    (void*)&out, (void*)&cntp
  };
  hipLaunchCooperativeKernel((void*)seq2seq_main, dim3(NBLK), dim3(NTHR),
                             kargs, 0, stream);
}